// Round 2
// baseline (200.089 us; speedup 1.0000x reference)
//
#include <hip/hip_runtime.h>
#include <math.h>
#include <float.h>

// x: (T,B,C,W,H) = (128,8,32,32,32) f32. Per-pixel linear recurrences over t.
// drive-normalization (y1/max y1) cancels inside the second linear scan, so a
// single forward pass per pixel suffices (track un-normalized y2' and its max).
//
// R1 structure: 2 pixels/thread via float2 loads (8 B/lane), t-loop split at
// tc (kills the per-iteration t==tc compare+cndmask), unroll 16 so ~16 loads
// (8 KB/wave) stay in flight -> latency-bound 1.7 TB/s should move toward BW.
#define T_STEPS 128
#define NPIX   (8 * 32 * 32 * 32)   // 262144 pixels per t-slice
#define CHW    (32 * 32 * 32)       // param broadcast period
#define NPAIR  (NPIX / 2)           // 131072 float2 columns

__global__ __launch_bounds__(256) void divnorm_kernel(
    const float* __restrict__ x,
    const float* __restrict__ tau1,
    const float* __restrict__ tau2,
    const float* __restrict__ sigma,
    const float* __restrict__ nexp,
    const int*   __restrict__ t_sel,
    float* __restrict__ out)
{
    const int pr = blockIdx.x * blockDim.x + threadIdx.x;   // pair index
    if (pr >= NPAIR) return;
    const int pix = pr << 1;              // even -> float2 loads are 8B-aligned
    const int chw = pix & (CHW - 1);

    const float2 tv1 = *(const float2*)(tau1 + chw);
    const float2 tv2 = *(const float2*)(tau2 + chw);
    const float a1x = expf(-1.0f / tv1.x), a1y = expf(-1.0f / tv1.y);
    const float a2x = expf(-1.0f / tv2.x), a2y = expf(-1.0f / tv2.y);
    const int tc = *t_sel;                // 100, uniform

    // State. y1[t] = Bm at entry of iter t (y1[0]=0); y2'[t] = c2 at entry.
    float Ax = 0.f, Ay = 0.f, Bmx = 0.f, Bmy = 0.f, c2x = 0.f, c2y = 0.f;
    float m1x = -INFINITY, m1y = -INFINITY, m2x = -INFINITY, m2y = -INFINITY;

    const float2* xp = (const float2*)x + pr;

#define STEP(xvx, xvy) do {                                   \
        m1x = fmaxf(m1x, Bmx);  m1y = fmaxf(m1y, Bmy);        \
        m2x = fmaxf(m2x, c2x);  m2y = fmaxf(m2y, c2y);        \
        c2x = fmaf(a2x, c2x, Bmx);                            \
        c2y = fmaf(a2y, c2y, Bmy);                            \
        const float nAx = fmaf(a1x, Ax, (xvx));               \
        const float nAy = fmaf(a1y, Ay, (xvy));               \
        Bmx = a1x * (Bmx + Ax);                               \
        Bmy = a1y * (Bmy + Ay);                               \
        Ax = nAx; Ay = nAy;                                   \
    } while (0)

    int t = 0;
    #pragma unroll 16
    for (; t < tc; ++t) {
        const float2 xv = xp[(size_t)t * NPAIR];
        STEP(xv.x, xv.y);
    }
    // y1[tc], y2'[tc] are the state at entry to iteration tc
    const float y1cx = Bmx, y1cy = Bmy, y2cx = c2x, y2cy = c2y;
    #pragma unroll 16
    for (; t < T_STEPS; ++t) {
        const float2 xv = xp[(size_t)t * NPAIR];
        STEP(xv.x, xv.y);
    }
#undef STEP

    const float2 nv = *(const float2*)(nexp  + chw);
    const float2 sg = *(const float2*)(sigma + chw);

    float2 r;
    {
        const float drive = y1cx / m1x;
        const float norm  = y2cx / m2x;
        const float id = fabsf(powf(drive, nv.x));
        const float nr = fabsf(powf(norm,  nv.x)) + sg.x;
        float v = id / nr;
        if (isnan(v)) v = 0.0f; else if (isinf(v)) v = copysignf(FLT_MAX, v);
        r.x = v;
    }
    {
        const float drive = y1cy / m1y;
        const float norm  = y2cy / m2y;
        const float id = fabsf(powf(drive, nv.y));
        const float nr = fabsf(powf(norm,  nv.y)) + sg.y;
        float v = id / nr;
        if (isnan(v)) v = 0.0f; else if (isinf(v)) v = copysignf(FLT_MAX, v);
        r.y = v;
    }
    *((float2*)out + pr) = r;
}

extern "C" void kernel_launch(void* const* d_in, const int* in_sizes, int n_in,
                              void* d_out, int out_size, void* d_ws, size_t ws_size,
                              hipStream_t stream) {
    const float* x     = (const float*)d_in[0];
    const float* tau1  = (const float*)d_in[1];
    const float* tau2  = (const float*)d_in[2];
    const float* sigma = (const float*)d_in[3];
    const float* nexp  = (const float*)d_in[4];
    const int*   t_sel = (const int*)d_in[5];
    float* out = (float*)d_out;

    const int threads = 256;
    const int blocks  = NPAIR / threads;   // 512 blocks
    divnorm_kernel<<<blocks, threads, 0, stream>>>(x, tau1, tau2, sigma, nexp, t_sel, out);
}

// Round 3
// 197.478 us; speedup vs baseline: 1.0132x; 1.0132x over previous
//
#include <hip/hip_runtime.h>
#include <math.h>
#include <float.h>

// x: (T,B,C,W,H) = (128,8,32,32,32) f32. Per-pixel linear recurrences over t;
// drive-normalization (y1/max y1) cancels inside the second linear scan, so a
// single forward pass per pixel suffices (track un-normalized y2' + its max).
//
// R2: explicit double-buffered register prefetch. The recurrence serializes
// consumption, so without an explicit buffer the scheduler interleaves
// load->wait->use (few lines in flight -> ~1.7 TB/s). Here body b+1's 16
// loads are issued before body b's compute; steady state 16-32 loads in
// flight per wave, 16 waves/CU (1024 blocks). Everything fully unrolled
// (compile-time trip counts).
#define T_STEPS 128
#define NPIX   (8 * 32 * 32 * 32)   // 262144 pixels per t-slice
#define CHW    (32 * 32 * 32)       // param broadcast period
#define UB     16                   // prefetch body size
#define NBODY  (T_STEPS / UB)       // 8

__global__ __launch_bounds__(256) void divnorm_kernel(
    const float* __restrict__ x,
    const float* __restrict__ tau1,
    const float* __restrict__ tau2,
    const float* __restrict__ sigma,
    const float* __restrict__ nexp,
    const int*   __restrict__ t_sel,
    float* __restrict__ out)
{
    const int pix = blockIdx.x * blockDim.x + threadIdx.x;
    if (pix >= NPIX) return;
    const int chw = pix & (CHW - 1);

    const float a1 = expf(-1.0f / tau1[chw]);
    const float a2 = expf(-1.0f / tau2[chw]);
    const int tc = *t_sel;   // 100, wave-uniform

    // y1[t] = Bm at entry of iter t (y1[0]=0); y2'[t] = c2 at entry.
    float A = 0.f, Bm = 0.f, c2 = 0.f;
    float m1 = -INFINITY, m2 = -INFINITY;
    float y1c = 0.f, y2c = 0.f;

    const float* xp = x + pix;

    float buf[2][UB];
    #pragma unroll
    for (int j = 0; j < UB; ++j)            // prologue: body 0 loads
        buf[0][j] = xp[(size_t)j * NPIX];

    #pragma unroll
    for (int b = 0; b < NBODY; ++b) {
        const int cur = b & 1, nxt = cur ^ 1;
        if (b + 1 < NBODY) {                // prefetch body b+1 (16 loads)
            #pragma unroll
            for (int j = 0; j < UB; ++j)
                buf[nxt][j] = xp[(size_t)((b + 1) * UB + j) * NPIX];
        }
        #pragma unroll
        for (int j = 0; j < UB; ++j) {      // consume body b
            const int t = b * UB + j;
            if (t == tc) { y1c = Bm; y2c = c2; }   // uniform (SGPR) compare
            m1 = fmaxf(m1, Bm);
            m2 = fmaxf(m2, c2);
            c2 = fmaf(a2, c2, Bm);                 // uses entry Bm
            const float nA = fmaf(a1, A, buf[cur][j]);
            Bm = a1 * (Bm + A);                    // uses entry A
            A = nA;
        }
    }

    // drive[tc] = y1[tc]/max_t y1 ; norm[tc] = y2'[tc]/max_t y2' (M1 cancels)
    const float drive = y1c / m1;
    const float norm  = y2c / m2;
    const float nv    = nexp[chw];
    const float id    = fabsf(powf(drive, nv));
    const float nr    = fabsf(powf(norm,  nv)) + sigma[chw];
    float r = id / nr;
    // jnp.nan_to_num defaults: nan->0, +inf->FLT_MAX, -inf->-FLT_MAX
    if (isnan(r))      r = 0.0f;
    else if (isinf(r)) r = copysignf(FLT_MAX, r);
    out[pix] = r;
}

extern "C" void kernel_launch(void* const* d_in, const int* in_sizes, int n_in,
                              void* d_out, int out_size, void* d_ws, size_t ws_size,
                              hipStream_t stream) {
    const float* x     = (const float*)d_in[0];
    const float* tau1  = (const float*)d_in[1];
    const float* tau2  = (const float*)d_in[2];
    const float* sigma = (const float*)d_in[3];
    const float* nexp  = (const float*)d_in[4];
    const int*   t_sel = (const int*)d_in[5];
    float* out = (float*)d_out;

    const int threads = 256;
    const int blocks  = NPIX / threads;     // 1024 blocks -> 16 waves/CU
    divnorm_kernel<<<blocks, threads, 0, stream>>>(x, tau1, tau2, sigma, nexp, t_sel, out);
}